// Round 1
// baseline (325.564 us; speedup 1.0000x reference)
//
#include <hip/hip_runtime.h>
#include <hip/hip_bf16.h>

typedef __bf16 bf16;
typedef __bf16 bf16x8 __attribute__((ext_vector_type(8)));
typedef __bf16 bf16x4 __attribute__((ext_vector_type(4)));
typedef float  f32x4  __attribute__((ext_vector_type(4)));

#define MFMA16(A,B,C) __builtin_amdgcn_mfma_f32_16x16x32_bf16((A),(B),(C),0,0,0)

constexpr int NI    = 64;     // instances
constexpr int NN    = 128;    // N (embedding rows / output cols)
constexpr int E     = 256;    // embed dim
constexpr int HID   = 1024;   // hidden
constexpr int BATCH = 2048;
constexpr int BM    = 128;    // batch rows per block
constexpr int BH    = 64;     // hidden chunk
// fallback-path LDS strides (old kernel)
constexpr int W1P   = E  + 8;
constexpr int W2P   = BH + 8;
constexpr int HP    = BH + 8;

__device__ __forceinline__ void glds16(const void* g, void* l) {
    // width=16 global->LDS DMA; LDS dest = wave-uniform base + lane*16 (HW),
    // global src is per-lane.
    __builtin_amdgcn_global_load_lds(
        (const __attribute__((address_space(1))) unsigned int*)g,
        (__attribute__((address_space(3))) unsigned int*)l, 16, 0, 0);
}

__device__ __forceinline__ float fast_gelu(float x) {
    float p = 1.5957691216f * __builtin_fmaf(0.044715f * x * x, x, x);
    return x * __builtin_amdgcn_rcpf(1.0f + __expf(-p));
}

// ---------------------------------------------------------------------------
// pack_w1: lin f32 [NI][E][HID] -> w1t bf16 "LDS image":
//   [i][h][p][j] = lin[ e=(p^(h&7))*8+j ][h]   (p: 16B chunk 0..31, j 0..7)
// Per (i, 64-h tile) the 32KB output block is CONTIGUOUS -> fused kernel
// stages it with linear global_load_lds; XOR swizzle makes sW1 ds_read_b128
// bank-conflict-free (8 lanes/16B-window, uniform).
// ---------------------------------------------------------------------------
__global__ __launch_bounds__(256) void pack_w1(
    const float* __restrict__ in, bf16* __restrict__ out)
{
    __shared__ __align__(16) bf16 t[64][264];   // [h_local][e], 528B rows (16B-aligned, 4 mod 32 dwords)
    const int inst = blockIdx.y;
    const int h0   = blockIdx.x * 64;
    const int tid  = threadIdx.x;
    {
        const int hq = tid & 15;               // 16 lanes x 4 h = 64 h
        const int e0 = tid >> 4;               // 16 e-rows / iter
        const float* ip = in + (size_t)inst * E * HID + h0 + hq * 4;
        #pragma unroll
        for (int it = 0; it < 16; ++it) {
            int e = it * 16 + e0;
            f32x4 v = *(const f32x4*)(ip + (size_t)e * HID);
            #pragma unroll
            for (int k = 0; k < 4; ++k) t[hq * 4 + k][e] = (bf16)v[k];
        }
    }
    __syncthreads();
    bf16* op = out + ((size_t)inst * HID + h0) * E;   // 64 rows x 512B, contiguous
    #pragma unroll
    for (int it = 0; it < 8; ++it) {
        int o  = it * 256 + tid;
        int hl = o >> 5, p = o & 31;
        int tt = p ^ (hl & 7);
        bf16x8 v = *(const bf16x8*)&t[hl][tt * 8];
        *(bf16x8*)(op + (size_t)o * 8) = v;
    }
}

// ---------------------------------------------------------------------------
// pack_w2: une f32 [NI][HID][NN] -> w2t bf16 [i][n][c][p][j], where for
//   t = p^(n&7), k2=t>>2, q=t&3:
//   j<4:  h = c*64 + k2*32 + q*4 + j
//   j>=4: h = c*64 + k2*32 + 16 + q*4 + (j-4)
// This bakes BOTH the GEMM2 K-permutation (so the in-register gelu'd H tiles
// are a legal A-fragment) AND the XOR bank swizzle into global layout.
// ---------------------------------------------------------------------------
__global__ __launch_bounds__(256) void pack_w2(
    const float* __restrict__ in, bf16* __restrict__ out)
{
    __shared__ __align__(16) bf16 t[128][68];   // [n][h_local], 136B rows (8B-aligned)
    const int inst = blockIdx.y;
    const int c    = blockIdx.x;                // 64-h chunk
    const int tid  = threadIdx.x;
    {
        const int nq = tid & 31;               // 32 lanes x 4 n = 128 n
        const int h0 = tid >> 5;               // 8 h-rows / iter
        const float* ip = in + ((size_t)inst * HID + c * 64) * NN + nq * 4;
        #pragma unroll
        for (int it = 0; it < 8; ++it) {
            int h = it * 8 + h0;
            f32x4 v = *(const f32x4*)(ip + (size_t)h * NN);
            #pragma unroll
            for (int k = 0; k < 4; ++k) t[nq * 4 + k][h] = (bf16)v[k];
        }
    }
    __syncthreads();
    bf16* ob = out + (size_t)inst * NN * HID + (size_t)c * 64;  // [n] stride 1024 elems
    #pragma unroll
    for (int it = 0; it < 4; ++it) {
        int o = it * 256 + tid;
        int n = o >> 3, p = o & 7;
        int tt = p ^ (n & 7);
        int k2 = tt >> 2, qq = tt & 3;
        const bf16* r0 = &t[n][k2 * 32 + qq * 4];
        bf16x4 lo = *(const bf16x4*)r0;
        bf16x4 hi = *(const bf16x4*)(r0 + 16);
        bf16x8 v;
        v[0] = lo[0]; v[1] = lo[1]; v[2] = lo[2]; v[3] = lo[3];
        v[4] = hi[0]; v[5] = hi[1]; v[6] = hi[2]; v[7] = hi[3];
        *(bf16x8*)(ob + (size_t)n * 1024 + p * 8) = v;
    }
}

// ---------------------------------------------------------------------------
// Fused MLP v2. Operand-swapped GEMM1 (computes S^T) so gelu(H) feeds GEMM2's
// A-operand straight from registers -> no sH LDS round-trip. Weights staged
// via global_load_lds from pre-packed/pre-swizzled images. LDS 48KB -> 3 blk/CU.
// ---------------------------------------------------------------------------
__global__ __launch_bounds__(256, 3) void mlp3_fused_v2(
    const int*   __restrict__ a,
    const float* __restrict__ embL,
    const float* __restrict__ embR,
    const bf16*  __restrict__ W1,   // packed [NI][HID][32 chunk][8]
    const bf16*  __restrict__ W2,   // packed [NI][NN][16 c][8 chunk][8]
    float* __restrict__ out)
{
    __shared__ __align__(16) bf16 sW1[BH * E];   // 32 KB, [hl][swizzled 16B chunks]
    __shared__ __align__(16) bf16 sW2[NN * BH];  // 16 KB, [n][swizzled 16B chunks]

    // XCD swizzle: 16 consecutive blocks per XCD share an instance -> weights L2-hot.
    const int blk   = blockIdx.x;
    const int xcd   = blk & 7;
    const int j     = blk >> 3;
    const int inst  = xcd + 8 * (j >> 4);
    const int btile = j & 15;

    const int tid  = threadIdx.x;
    const int wave = tid >> 6;
    const int lane = tid & 63;
    const int m  = lane & 15;
    const int q  = lane >> 4;
    const int xm = m & 7;           // per-lane XOR swizzle mask

    // ---- A fragments: this wave's 32 batch rows x 256 e, bf16 in registers ----
    bf16x8 aF[2][8];
    #pragma unroll
    for (int rt = 0; rt < 2; ++rt) {
        const int r  = btile * BM + wave * 32 + rt * 16 + m;
        const int i1 = a[2 * r + 0];
        const int i2 = a[2 * r + 1];
        const float* pl = embL + ((size_t)inst * NN + i1) * E;
        const float* pr = embR + ((size_t)inst * NN + i2) * E;
        #pragma unroll
        for (int ks = 0; ks < 8; ++ks) {
            const int e0 = ks * 32 + q * 8;
            f32x4 l0 = *(const f32x4*)(pl + e0);
            f32x4 l1 = *(const f32x4*)(pl + e0 + 4);
            f32x4 r0 = *(const f32x4*)(pr + e0);
            f32x4 r1 = *(const f32x4*)(pr + e0 + 4);
            bf16x8 s;
            #pragma unroll
            for (int k = 0; k < 4; ++k) {
                s[k]     = (bf16)(l0[k] + r0[k]);
                s[k + 4] = (bf16)(l1[k] + r1[k]);
            }
            aF[rt][ks] = s;
        }
    }

    f32x4 O[2][8];
    #pragma unroll
    for (int rt = 0; rt < 2; ++rt)
        #pragma unroll
        for (int ct = 0; ct < 8; ++ct)
            O[rt][ct] = (f32x4){0.f, 0.f, 0.f, 0.f};

    const char* w1g = (const char*)W1 + (size_t)inst * (HID * E * 2);
    const char* w2g = (const char*)W2 + (size_t)inst * (NN * HID * 2);
    char* s1 = (char*)sW1;
    char* s2 = (char*)sW2;

    #pragma unroll 1
    for (int c = 0; c < HID / BH; ++c) {
        __syncthreads();   // prev chunk's LDS reads done before restage
        {   // stage W1: 32KB contiguous; W2: 16KB (strided rows), via glds DMA
            const char* g1 = w1g + c * (BH * E * 2);
            #pragma unroll
            for (int it = 0; it < 8; ++it) {
                const int b = it * 4 + wave;
                glds16(g1 + b * 1024 + lane * 16, s1 + b * 1024);
            }
            const char* g2 = w2g + c * 128;
            #pragma unroll
            for (int it = 0; it < 4; ++it) {
                const int b = it * 4 + wave;
                const int n = b * 8 + (lane >> 3);
                glds16(g2 + (size_t)n * 2048 + (lane & 7) * 16, s2 + b * 1024);
            }
        }
        __syncthreads();   // compiler drains vmcnt(0) before s_barrier

        #pragma unroll
        for (int k2 = 0; k2 < 2; ++k2) {
            bf16x8 pa[2];
            #pragma unroll
            for (int cth = 0; cth < 2; ++cth) {
                const int ct = k2 * 2 + cth;
                // GEMM1 (swapped): S^T tile = mfma(W1frag, aF)
                f32x4 S0 = (f32x4){0.f, 0.f, 0.f, 0.f};
                f32x4 S1 = (f32x4){0.f, 0.f, 0.f, 0.f};
                #pragma unroll
                for (int ks = 0; ks < 8; ++ks) {
                    const int sw = ((ks * 4 + q) ^ xm) * 16;
                    bf16x8 w1f = *(const bf16x8*)(s1 + (ct * 16 + m) * 512 + sw);
                    S0 = MFMA16(w1f, aF[0][ks], S0);
                    S1 = MFMA16(w1f, aF[1][ks], S1);
                }
                // gelu + pack: lane holds 4 h-consecutive values per tile
                #pragma unroll
                for (int rr = 0; rr < 4; ++rr) {
                    pa[0][cth * 4 + rr] = (bf16)fast_gelu(S0[rr]);
                    pa[1][cth * 4 + rr] = (bf16)fast_gelu(S1[rr]);
                }
            }
            // GEMM2: A = pa (registers), B = packed W2 (K-permutation baked in)
            #pragma unroll
            for (int ct2 = 0; ct2 < 8; ++ct2) {
                const int sw = ((k2 * 4 + q) ^ xm) * 16;
                bf16x8 w2f = *(const bf16x8*)(s2 + (ct2 * 16 + m) * 128 + sw);
                O[0][ct2] = MFMA16(pa[0], w2f, O[0][ct2]);
                O[1][ct2] = MFMA16(pa[1], w2f, O[1][ct2]);
            }
        }
    }

    // ---- epilogue: out[b, inst, n] fp32 ----
    #pragma unroll
    for (int rt = 0; rt < 2; ++rt)
        #pragma unroll
        for (int ct = 0; ct < 8; ++ct)
            #pragma unroll
            for (int rr = 0; rr < 4; ++rr) {
                const int b = btile * BM + wave * 32 + rt * 16 + q * 4 + rr;
                const int n = ct * 16 + m;
                out[((size_t)b * NI + inst) * NN + n] = O[rt][ct][rr];
            }
}

// ---------------------------------------------------------------------------
// Fallback (no workspace): previous-session kernel, f32 weights, in-kernel
// transpose through LDS. Unchanged.
// ---------------------------------------------------------------------------
__global__ __launch_bounds__(256, 2) void mlp3_fallback(
    const int*   __restrict__ a,
    const float* __restrict__ embL,
    const float* __restrict__ embR,
    const float* __restrict__ W1,   // [NI][E][HID] f32
    const float* __restrict__ W2,   // [NI][HID][NN] f32
    float* __restrict__ out)
{
    __shared__ __align__(16) bf16 sW1[BH][W1P];
    __shared__ __align__(16) bf16 sW2[NN][W2P];
    __shared__ __align__(16) bf16 sH [BM][HP];

    const int blk   = blockIdx.x;
    const int xcd   = blk & 7;
    const int j     = blk >> 3;
    const int inst  = xcd + 8 * (j >> 4);
    const int btile = j & 15;

    const int tid  = threadIdx.x;
    const int wave = tid >> 6;
    const int lane = tid & 63;
    const int m = lane & 15;
    const int q = lane >> 4;

    bf16x8 aF[2][8];
    #pragma unroll
    for (int rt = 0; rt < 2; ++rt) {
        const int r  = btile * BM + wave * 32 + rt * 16 + m;
        const int i1 = a[2 * r + 0];
        const int i2 = a[2 * r + 1];
        const float* pl = embL + ((size_t)inst * NN + i1) * E;
        const float* pr = embR + ((size_t)inst * NN + i2) * E;
        #pragma unroll
        for (int ks = 0; ks < 8; ++ks) {
            const int e0 = ks * 32 + q * 8;
            f32x4 l0 = *(const f32x4*)(pl + e0);
            f32x4 l1 = *(const f32x4*)(pl + e0 + 4);
            f32x4 r0 = *(const f32x4*)(pr + e0);
            f32x4 r1 = *(const f32x4*)(pr + e0 + 4);
            bf16x8 s;
            #pragma unroll
            for (int k = 0; k < 4; ++k) {
                s[k]     = (bf16)(l0[k] + r0[k]);
                s[k + 4] = (bf16)(l1[k] + r1[k]);
            }
            aF[rt][ks] = s;
        }
    }

    f32x4 O[2][8];
    #pragma unroll
    for (int rt = 0; rt < 2; ++rt)
        #pragma unroll
        for (int ct = 0; ct < 8; ++ct)
            O[rt][ct] = (f32x4){0.f, 0.f, 0.f, 0.f};

    #pragma unroll 1
    for (int c = 0; c < HID / BH; ++c) {
        __syncthreads();
        #pragma unroll
        for (int it = 0; it < 8; ++it) {
            const int idx = it * 256 + tid;
            const int e = idx >> 3, h8 = idx & 7;
            f32x4 v0 = *(const f32x4*)(W1 + ((size_t)inst * E + e) * HID + c * BH + h8 * 8);
            f32x4 v1 = *(const f32x4*)(W1 + ((size_t)inst * E + e) * HID + c * BH + h8 * 8 + 4);
            #pragma unroll
            for (int k = 0; k < 4; ++k) {
                sW1[h8 * 8 + k][e]     = (bf16)v0[k];
                sW1[h8 * 8 + k + 4][e] = (bf16)v1[k];
            }
        }
        #pragma unroll
        for (int it = 0; it < 4; ++it) {
            const int idx = it * 256 + tid;
            const int h = idx >> 4, n8 = idx & 15;
            f32x4 v0 = *(const f32x4*)(W2 + ((size_t)inst * HID + c * BH + h) * NN + n8 * 8);
            f32x4 v1 = *(const f32x4*)(W2 + ((size_t)inst * HID + c * BH + h) * NN + n8 * 8 + 4);
            #pragma unroll
            for (int k = 0; k < 4; ++k) {
                sW2[n8 * 8 + k][h]     = (bf16)v0[k];
                sW2[n8 * 8 + k + 4][h] = (bf16)v1[k];
            }
        }
        __syncthreads();

        f32x4 S[2][4];
        #pragma unroll
        for (int rt = 0; rt < 2; ++rt)
            #pragma unroll
            for (int ct = 0; ct < 4; ++ct) S[rt][ct] = (f32x4){0.f, 0.f, 0.f, 0.f};
        #pragma unroll
        for (int ks = 0; ks < 8; ++ks) {
            #pragma unroll
            for (int ct = 0; ct < 4; ++ct) {
                bf16x8 b = *(const bf16x8*)&sW1[ct * 16 + m][ks * 32 + q * 8];
                S[0][ct] = MFMA16(aF[0][ks], b, S[0][ct]);
                S[1][ct] = MFMA16(aF[1][ks], b, S[1][ct]);
            }
        }

        #pragma unroll
        for (int rt = 0; rt < 2; ++rt)
            #pragma unroll
            for (int ct = 0; ct < 4; ++ct)
                #pragma unroll
                for (int rr = 0; rr < 4; ++rr)
                    sH[wave * 32 + rt * 16 + q * 4 + rr][ct * 16 + m] =
                        (bf16)fast_gelu(S[rt][ct][rr]);
        asm volatile("s_waitcnt lgkmcnt(0)" ::: "memory");

        #pragma unroll
        for (int k2 = 0; k2 < 2; ++k2) {
            bf16x8 h0 = *(const bf16x8*)&sH[wave * 32 +  0 + m][k2 * 32 + q * 8];
            bf16x8 h1 = *(const bf16x8*)&sH[wave * 32 + 16 + m][k2 * 32 + q * 8];
            #pragma unroll
            for (int ct = 0; ct < 8; ++ct) {
                bf16x8 b = *(const bf16x8*)&sW2[ct * 16 + m][k2 * 32 + q * 8];
                O[0][ct] = MFMA16(h0, b, O[0][ct]);
                O[1][ct] = MFMA16(h1, b, O[1][ct]);
            }
        }
    }

    #pragma unroll
    for (int rt = 0; rt < 2; ++rt)
        #pragma unroll
        for (int ct = 0; ct < 8; ++ct)
            #pragma unroll
            for (int rr = 0; rr < 4; ++rr) {
                const int b = btile * BM + wave * 32 + rt * 16 + q * 4 + rr;
                const int n = ct * 16 + m;
                out[((size_t)b * NI + inst) * NN + n] = O[rt][ct][rr];
            }
}

extern "C" void kernel_launch(void* const* d_in, const int* in_sizes, int n_in,
                              void* d_out, int out_size, void* d_ws, size_t ws_size,
                              hipStream_t stream)
{
    const int*   a    = (const int*)d_in[0];
    const float* embL = (const float*)d_in[1];
    const float* embR = (const float*)d_in[2];
    const float* lin  = (const float*)d_in[3];   // [NI][E][HID] f32
    const float* une  = (const float*)d_in[4];   // [NI][HID][NN] f32
    float* out = (float*)d_out;

    const size_t w1t_elems = (size_t)NI * HID * E;   // 16.78M bf16
    const size_t w2t_elems = (size_t)NI * NN * HID;  //  8.39M bf16
    const size_t need = (w1t_elems + w2t_elems) * sizeof(bf16);  // ~50 MB

    const int nblocks = (BATCH / BM) * NI;  // 1024

    if (ws_size >= need) {
        bf16* w1t = (bf16*)d_ws;
        bf16* w2t = w1t + w1t_elems;
        pack_w1<<<dim3(HID / 64, NI), 256, 0, stream>>>(lin, w1t);
        pack_w2<<<dim3(HID / BH, NI), 256, 0, stream>>>(une, w2t);
        mlp3_fused_v2<<<nblocks, 256, 0, stream>>>(
            a, embL, embR, w1t, w2t, out);
    } else {
        mlp3_fallback<<<nblocks, 256, 0, stream>>>(
            a, embL, embR, lin, une, out);
    }
}